// Round 5
// baseline (1014.200 us; speedup 1.0000x reference)
//
#include <hip/hip_runtime.h>
#include <math.h>
#include <stdint.h>

#define HP 256
#define PTS 8                 // points per workgroup
#define ROWS 64               // 8 points x 8 channels (ch7 dummy)
#define PSTR 264              // halves per plane row (264*2B; dw-stride 132 == 4 mod 32, proven 0-conflict)
#define NLAYER 6
#define WT_ELEMS (6*256*256)  // per hi/lo array, fp16

typedef _Float16 half8 __attribute__((ext_vector_type(8)));
typedef float  float16v __attribute__((ext_vector_type(16)));

// f32 extras section (float offsets within section)
#define C_WI 0                // [3][256]
#define C_BI 768              // [256]
#define C_BH 1024             // [6][256]
#define C_WO 2560             // [256][4]
#define C_TOT 3584

__device__ __forceinline__ float fast_tanh(float x) {
    float e = __expf(2.0f * x);
    return 1.0f - __fdividef(2.0f, e + 1.0f);
}

__device__ __forceinline__ float16v zero16() {
    float16v z;
    #pragma unroll
    for (int i = 0; i < 16; ++i) z[i] = 0.0f;
    return z;
}

// ---------------- prep: transpose + split weights ----------------
__global__ void prep_kernel(const float* __restrict__ W_in, const float* __restrict__ b_in,
                            const float* __restrict__ W_h,  const float* __restrict__ b_h,
                            const float* __restrict__ W_out, void* __restrict__ wsv)
{
    _Float16* wt_hi = (_Float16*)wsv;
    _Float16* wt_lo = wt_hi + WT_ELEMS;
    float* cf = (float*)((char*)wsv + (size_t)2 * WT_ELEMS * 2);

    int i0 = blockIdx.x * blockDim.x + threadIdx.x;
    int stride = gridDim.x * blockDim.x;
    for (int i = i0; i < WT_ELEMS; i += stride) {
        int l = i >> 16, n = (i >> 8) & 255, k = i & 255;
        float w = (n < 250 && k < 250) ? W_h[(l*250 + k)*250 + n] : 0.0f;  // Wt[l][n][k]
        _Float16 h = (_Float16)w;
        _Float16 lo = (_Float16)((w - (float)h) * 1024.0f);
        wt_hi[i] = h; wt_lo[i] = lo;
    }
    for (int i = i0; i < C_TOT; i += stride) {
        float v = 0.0f;
        if (i < C_BI) { int r = i >> 8, j = i & 255; if (j < 250) v = W_in[r*250 + j]; }
        else if (i < C_BH) { int j = i - C_BI; if (j < 250) v = b_in[j]; }
        else if (i < C_WO) { int idx = i - C_BH; int l = idx >> 8, j = idx & 255; if (j < 250) v = b_h[l*250 + j]; }
        else { int idx = i - C_WO; int k = idx >> 2, o = idx & 3; if (k < 250) v = W_out[k*4 + o]; }
        cf[i] = v;
    }
}

// ---------------- fused PINN kernel ----------------
// 256 threads = 4 waves. Wave w owns cols 64*w..64*w+63 (two 32-col subtiles t=0,1)
// and ALL 64 rows (two 32-row tiles rt=0,1). MFMA 32x32x16 f16, 2-chain hi/lo comp.
// A stored as separate hi/lo f16 planes (no unpack VALU); A(s+1) + B(s+2) prefetch.
__launch_bounds__(256, 2)
__global__ void pinn_mfma(const float* __restrict__ xg, const float* __restrict__ yg,
                          const float* __restrict__ tg, const void* __restrict__ wsv,
                          const float* __restrict__ b_out, const float* __restrict__ act,
                          float* __restrict__ out, int N)
{
    __shared__ _Float16 Ah[ROWS * PSTR];
    __shared__ _Float16 Al[ROWS * PSTR];
    __shared__ float zo[PTS][28];

    const _Float16* __restrict__ wt_hi = (const _Float16*)wsv;
    const _Float16* __restrict__ wt_lo = wt_hi + WT_ELEMS;
    const float* __restrict__ cf = (const float*)((const char*)wsv + (size_t)2 * WT_ELEMS * 2);

    const int tid  = threadIdx.x;
    const int lane = tid & 63;
    const int qtr  = tid >> 6;        // col quarter: 64*qtr
    const int lo5  = lane & 31;
    const int hi5  = lane >> 5;

    // ---------- input layer jet: thread j = tid handles neuron j for all 8 points ----------
    {
        int j = tid;
        float wi0 = cf[C_WI + j], wi1 = cf[C_WI + 256 + j], wi2 = cf[C_WI + 512 + j];
        float biv = cf[C_BI + j];
        float c0 = 10.0f * act[0];
        #pragma unroll
        for (int p = 0; p < PTS; ++p) {
            int gp = blockIdx.x * PTS + p;
            gp = gp < N ? gp : N - 1;
            float px = xg[gp], py = yg[gp], pt = tg[gp];
            float z = px*wi0 + py*wi1 + pt*wi2 + biv;
            float y = fast_tanh(c0 * z);
            float s = 1.0f - y*y;
            float cs = c0 * s;
            float m2 = -2.0f * c0 * cs * y;
            float o[8];
            o[0] = y;           o[1] = cs*wi0;      o[2] = cs*wi1;      o[3] = cs*wi2;
            o[4] = m2*wi0*wi0;  o[5] = m2*wi1*wi1;  o[6] = m2*wi0*wi1;  o[7] = 0.0f;
            #pragma unroll
            for (int c = 0; c < 8; ++c) {
                _Float16 h = (_Float16)o[c];
                Ah[(8*p + c)*PSTR + j] = h;
                Al[(8*p + c)*PSTR + j] = (_Float16)((o[c] - (float)h) * 1024.0f);
            }
        }
    }

    // ---------- hidden layers ----------
    for (int L = 0; L < NLAYER; ++L) {
        float cc = 10.0f * act[L + 1];
        const _Float16* __restrict__ wbh = wt_hi + ((size_t)L << 16);
        const _Float16* __restrict__ wbl = wt_lo + ((size_t)L << 16);

        const int n0 = 64*qtr + lo5;                  // t=0 output neuron
        const _Float16* ph0 = wbh + (size_t)n0 * 256 + 8*hi5;
        const _Float16* pl0 = wbl + (size_t)n0 * 256 + 8*hi5;
        const _Float16* ph1 = ph0 + 32 * 256;         // t=1: n0+32
        const _Float16* pl1 = pl0 + 32 * 256;

        // B prefetch (global, read-only) issued BEFORE the barrier to hide its drain
        half8 b0h = *(const half8*)(ph0);
        half8 b0l = *(const half8*)(pl0);
        half8 b1h = *(const half8*)(ph1);
        half8 b1l = *(const half8*)(pl1);
        half8 n0h = *(const half8*)(ph0 + 16);
        half8 n0l = *(const half8*)(pl0 + 16);
        half8 n1h = *(const half8*)(ph1 + 16);
        half8 n1l = *(const half8*)(pl1 + 16);

        float16v m00 = zero16(), m01 = zero16(), m10 = zero16(), m11 = zero16();
        float16v c00 = zero16(), c01 = zero16(), c10 = zero16(), c11 = zero16();

        __syncthreads();                              // Apack planes stable

        const int abase = lo5 * PSTR + 8*hi5;
        half8 a0h = *(const half8*)&Ah[abase];
        half8 a0l = *(const half8*)&Al[abase];
        half8 a1h = *(const half8*)&Ah[abase + 32*PSTR];
        half8 a1l = *(const half8*)&Al[abase + 32*PSTR];

        #pragma unroll 4
        for (int s = 0; s < 16; ++s) {
            int so2 = 16 * ((s + 2) & 15);            // B prefetch distance 2 (wraps harmlessly)
            half8 p0h = *(const half8*)(ph0 + so2);
            half8 p0l = *(const half8*)(pl0 + so2);
            half8 p1h = *(const half8*)(ph1 + so2);
            half8 p1l = *(const half8*)(pl1 + so2);
            int sa = 16 * ((s + 1) & 15);             // A prefetch distance 1
            half8 na0h = *(const half8*)&Ah[abase + sa];
            half8 na0l = *(const half8*)&Al[abase + sa];
            half8 na1h = *(const half8*)&Ah[abase + 32*PSTR + sa];
            half8 na1l = *(const half8*)&Al[abase + 32*PSTR + sa];

            m00 = __builtin_amdgcn_mfma_f32_32x32x16_f16(a0h, b0h, m00, 0, 0, 0);
            m01 = __builtin_amdgcn_mfma_f32_32x32x16_f16(a1h, b0h, m01, 0, 0, 0);
            m10 = __builtin_amdgcn_mfma_f32_32x32x16_f16(a0h, b1h, m10, 0, 0, 0);
            m11 = __builtin_amdgcn_mfma_f32_32x32x16_f16(a1h, b1h, m11, 0, 0, 0);
            c00 = __builtin_amdgcn_mfma_f32_32x32x16_f16(a0h, b0l, c00, 0, 0, 0);
            c01 = __builtin_amdgcn_mfma_f32_32x32x16_f16(a1h, b0l, c01, 0, 0, 0);
            c10 = __builtin_amdgcn_mfma_f32_32x32x16_f16(a0h, b1l, c10, 0, 0, 0);
            c11 = __builtin_amdgcn_mfma_f32_32x32x16_f16(a1h, b1l, c11, 0, 0, 0);
            c00 = __builtin_amdgcn_mfma_f32_32x32x16_f16(a0l, b0h, c00, 0, 0, 0);
            c01 = __builtin_amdgcn_mfma_f32_32x32x16_f16(a1l, b0h, c01, 0, 0, 0);
            c10 = __builtin_amdgcn_mfma_f32_32x32x16_f16(a0l, b1h, c10, 0, 0, 0);
            c11 = __builtin_amdgcn_mfma_f32_32x32x16_f16(a1l, b1h, c11, 0, 0, 0);

            a0h = na0h; a0l = na0l; a1h = na1h; a1l = na1l;
            b0h = n0h;  b0l = n0l;  b1h = n1h;  b1l = n1l;
            n0h = p0h;  n0l = p0l;  n1h = p1h;  n1l = p1l;
        }

        __syncthreads();                              // all reads done before any overwrite

        float bb0 = cf[C_BH + (L << 8) + n0];         // hidden bias
        float bb1 = cf[C_BH + (L << 8) + n0 + 32];

        #pragma unroll
        for (int t = 0; t < 2; ++t) {
            float bb = t ? bb1 : bb0;
            int ncol = 64*qtr + 32*t + lo5;
            #pragma unroll
            for (int rt = 0; rt < 2; ++rt) {
                float16v mv = t ? (rt ? m11 : m10) : (rt ? m01 : m00);
                float16v cv = t ? (rt ? c11 : c10) : (rt ? c01 : c00);
                #pragma unroll
                for (int p = 0; p < 4; ++p) {
                    float za  = mv[4*p+0] + cv[4*p+0] * (1.0f/1024.0f);
                    float zb  = mv[4*p+1] + cv[4*p+1] * (1.0f/1024.0f);
                    float zc_ = mv[4*p+2] + cv[4*p+2] * (1.0f/1024.0f);
                    float zd  = mv[4*p+3] + cv[4*p+3] * (1.0f/1024.0f);
                    if (!hi5) za += bb;               // bias on value channel
                    float e0 = __shfl_xor(za, 32);
                    float e1 = __shfl_xor(zb, 32);
                    float e2 = __shfl_xor(zc_, 32);
                    float zval = hi5 ? e0 : za;
                    float y  = fast_tanh(cc * zval);
                    float sh = 1.0f - y*y;
                    float cs = cc * sh;
                    float o0, o1, o2, o3;
                    if (!hi5) {
                        o0 = y; o1 = cs*zb; o2 = cs*zc_; o3 = cs*zd;
                    } else {
                        float m2c = -2.0f * cc * cs * y;
                        float zx = e1, zy = e2;
                        o0 = cs*za  + m2c*zx*zx;      // ch4
                        o1 = cs*zb  + m2c*zy*zy;      // ch5
                        o2 = cs*zc_ + m2c*zx*zy;      // ch6
                        o3 = 0.0f;                    // ch7 dummy (hi5 half)
                    }
                    int rbase = (32*rt + 8*p + 4*hi5) * PSTR + ncol;
                    _Float16 h0 = (_Float16)o0;
                    Ah[rbase + 0*PSTR] = h0;
                    Al[rbase + 0*PSTR] = (_Float16)((o0 - (float)h0) * 1024.0f);
                    _Float16 h1 = (_Float16)o1;
                    Ah[rbase + 1*PSTR] = h1;
                    Al[rbase + 1*PSTR] = (_Float16)((o1 - (float)h1) * 1024.0f);
                    _Float16 h2 = (_Float16)o2;
                    Ah[rbase + 2*PSTR] = h2;
                    Al[rbase + 2*PSTR] = (_Float16)((o2 - (float)h2) * 1024.0f);
                    _Float16 h3 = (_Float16)o3;
                    Ah[rbase + 3*PSTR] = h3;
                    Al[rbase + 3*PSTR] = (_Float16)((o3 - (float)h3) * 1024.0f);
                }
            }
        }
    }

    // ---------- output layer: 28 dots per point ----------
    __syncthreads();
    if (tid < PTS * 28) {
        int p = tid / 28, idx = tid % 28;
        int c = idx >> 2, o = idx & 3;
        const _Float16* rh = &Ah[(8*p + c) * PSTR];
        const _Float16* rl = &Al[(8*p + c) * PSTR];
        float s = 0.0f;
        for (int k = 0; k < HP; ++k)
            s += ((float)rh[k] + (float)rl[k] * (1.0f/1024.0f)) * cf[C_WO + 4*k + o];
        zo[p][idx] = s;
    }
    __syncthreads();

    // ---------- heads + PDE residuals ----------
    if (tid < PTS) {
        int gp = blockIdx.x * PTS + tid;
        if (gp < N) {
            float zc[7][4];
            #pragma unroll
            for (int c = 0; c < 7; ++c)
                #pragma unroll
                for (int o = 0; o < 4; ++o)
                    zc[c][o] = zo[tid][c*4 + o] + (c == 0 ? b_out[o] : 0.0f);

            float u  = zc[0][0], vv = zc[0][1];
            float u_x = zc[1][0], u_y = zc[2][0], u_t = zc[3][0];
            float u_xx = zc[4][0], u_yy = zc[5][0];
            float v_x = zc[1][1], v_y = zc[2][1], v_t = zc[3][1];
            float v_xx = zc[4][1], v_yy = zc[5][1];

            float ep  = expf(zc[0][2]);
            float p_x = ep * zc[1][2], p_y = ep * zc[2][2];

            float a   = 1.0f / (1.0f + expf(-zc[0][3]));
            float sp  = a * (1.0f - a);
            float spp = sp * (1.0f - 2.0f*a);
            float z1a = zc[1][3], z2a = zc[2][3];
            float a_x = sp * z1a, a_y = sp * z2a, a_t = sp * zc[3][3];
            float a_xx = spp*z1a*z1a + sp*zc[4][3];
            float a_yy = spp*z2a*z2a + sp*zc[5][3];
            float a_xy = spp*z1a*z2a + sp*zc[6][3];

            float mu_x = -9.0f*a_x, mu_y = -9.0f*a_y;
            float mu   = 10.0f - 9.0f*a;
            float rr   = 1.0f - 0.9f*a;
            float g  = sqrtf(a_x*a_x + a_y*a_y + 2.220446049250313e-16f);
            float g3 = g*g*g;
            float curv = -((a_xx + a_yy)/g
                         - (a_x*a_x*a_xx + a_y*a_y*a_yy + 2.0f*a_x*a_y*a_xy)/g3);
            float one_Re   = mu   * 0.002f;
            float one_Re_x = mu_x * 0.002f;
            float one_Re_y = mu_y * 0.002f;

            float PDE_m = u_x + v_y;
            float PDE_a = a_t + u*a_x + vv*a_y;
            float PDE_u = (u_t + u*u_x + vv*u_y)*rr + p_x - 0.049f*curv*a_x
                        - one_Re*(u_xx + u_yy) - 2.0f*one_Re_x*u_x - one_Re_y*(u_y + v_x);
            float PDE_v = (v_t + u*v_x + vv*v_y)*rr + p_y - 0.049f*curv*a_y
                        - one_Re*(v_xx + v_yy) - rr*0.49f
                        - 2.0f*one_Re_y*v_y - one_Re_x*(u_y + v_x);

            out[0*N + gp] = PDE_m;
            out[1*N + gp] = PDE_u;
            out[2*N + gp] = PDE_v;
            out[3*N + gp] = PDE_a;
        }
    }
}

extern "C" void kernel_launch(void* const* d_in, const int* in_sizes, int n_in,
                              void* d_out, int out_size, void* d_ws, size_t ws_size,
                              hipStream_t stream)
{
    const float* x     = (const float*)d_in[0];
    const float* y     = (const float*)d_in[1];
    const float* t     = (const float*)d_in[2];
    const float* W_in  = (const float*)d_in[3];
    const float* b_in  = (const float*)d_in[4];
    const float* W_h   = (const float*)d_in[5];
    const float* b_h   = (const float*)d_in[6];
    const float* W_out = (const float*)d_in[7];
    const float* b_out = (const float*)d_in[8];
    const float* act   = (const float*)d_in[9];
    float* out = (float*)d_out;
    int N = in_sizes[0];

    hipLaunchKernelGGL(prep_kernel, dim3(512), dim3(256), 0, stream,
                       W_in, b_in, W_h, b_h, W_out, d_ws);
    int nb = (N + PTS - 1) / PTS;
    hipLaunchKernelGGL(pinn_mfma, dim3(nb), dim3(256), 0, stream,
                       x, y, t, d_ws, b_out, act, out, N);
}